// Round 4
// baseline (434.474 us; speedup 1.0000x reference)
//
#include <hip/hip_runtime.h>
#include <math.h>

// ---------------------------------------------------------------------------
// PermutedNetwork, R4: NHWC everywhere.
//  - deform gathers become float4 loads over contiguous channels
//  - layer-1 (CIN=1): input tile staged in LDS (halo 2, global fallback)
//  - occupancy raised (launch_bounds), channel splits sized per layer
// fp32 throughout (no fp32 MFMA on CDNA4).
// ---------------------------------------------------------------------------

// ---- Layer 1: fused offset-conv + deform + relu, CIN=1.
// Block = 16x16 spatial tile of one batch. Input tile in LDS (21x21 + pad).
__global__ __launch_bounds__(256, 6)
void deform1_fused(const float* __restrict__ x,    // [64,96,96]
                   const float* __restrict__ woff, // [18,1,3,3]
                   const float* __restrict__ boff, // [18]
                   const float* __restrict__ w1,   // [16,1,3,3]
                   const float* __restrict__ b1,   // [16]
                   float* __restrict__ out) {      // [64,96,96,16] NHWC
  const int H = 96, W = 96;
  __shared__ float tile[21 * 22];
  __shared__ float wos[9 * 18];
  __shared__ __align__(16) float ws1[9 * 16];
  int b = blockIdx.y;
  int tileid = blockIdx.x;                    // 0..35
  int by0 = (tileid / 6) * 16, bx0 = (tileid % 6) * 16;
  const float* xb = x + (size_t)b * H * W;

  for (int t = threadIdx.x; t < 9 * 18; t += 256) { int k = t / 18, tc = t % 18; wos[t] = woff[tc * 9 + k]; }
  for (int t = threadIdx.x; t < 9 * 16; t += 256) { int k = t / 16, o = t % 16; ws1[t] = w1[o * 9 + k]; }
  for (int t = threadIdx.x; t < 21 * 21; t += 256) {
    int r = t / 21, c = t % 21;
    int gy = min(max(by0 - 2 + r, 0), H - 1);
    int gx = min(max(bx0 - 2 + c, 0), W - 1);
    tile[r * 22 + c] = xb[gy * W + gx];
  }
  __syncthreads();

  int tx = threadIdx.x & 15, ty = threadIdx.x >> 4;
  int yi = by0 + ty, xi = bx0 + tx;

  float off[18];
#pragma unroll
  for (int tc = 0; tc < 18; ++tc) off[tc] = boff[tc];
#pragma unroll
  for (int ky = 0; ky < 3; ++ky) {
    int yy = yi + ky - 1;
    if (yy < 0 || yy >= H) continue;
#pragma unroll
    for (int kx = 0; kx < 3; ++kx) {
      int xx = xi + kx - 1;
      if (xx < 0 || xx >= W) continue;
      float v = tile[(ty + ky + 1) * 22 + (tx + kx + 1)];
      const float2* wv = (const float2*)&wos[(ky * 3 + kx) * 18];
#pragma unroll
      for (int tt = 0; tt < 9; ++tt) {
        float2 ww = wv[tt];
        off[2 * tt]     = fmaf(ww.x, v, off[2 * tt]);
        off[2 * tt + 1] = fmaf(ww.y, v, off[2 * tt + 1]);
      }
    }
  }

  float acc[16];
#pragma unroll
  for (int o = 0; o < 16; ++o) acc[o] = b1[o];

#pragma unroll
  for (int k = 0; k < 9; ++k) {
    float py = (float)(yi + k / 3 - 1) + off[2 * k];
    float px = (float)(xi + k % 3 - 1) + off[2 * k + 1];
    float y0f = floorf(py), x0f = floorf(px);
    float fy = py - y0f, fx = px - x0f;
    int y0 = (int)y0f, x0 = (int)x0f, y1 = y0 + 1, x1 = x0 + 1;
    float vy0 = (y0 >= 0 && y0 < H) ? 1.f : 0.f;
    float vy1 = (y1 >= 0 && y1 < H) ? 1.f : 0.f;
    float vx0 = (x0 >= 0 && x0 < W) ? 1.f : 0.f;
    float vx1 = (x1 >= 0 && x1 < W) ? 1.f : 0.f;
    float w00 = (1.f - fy) * (1.f - fx) * vy0 * vx0;
    float w01 = (1.f - fy) * fx * vy0 * vx1;
    float w10 = fy * (1.f - fx) * vy1 * vx0;
    float w11 = fy * fx * vy1 * vx1;
    int cy0 = min(max(y0, 0), H - 1), cy1 = min(max(y1, 0), H - 1);
    int cx0 = min(max(x0, 0), W - 1), cx1 = min(max(x1, 0), W - 1);
    float v00, v01, v10, v11;
    bool in_lds = (cy0 >= by0 - 2) && (cy1 <= by0 + 18) && (cx0 >= bx0 - 2) && (cx1 <= bx0 + 18);
    if (in_lds) {
      int r0 = cy0 - by0 + 2, r1 = cy1 - by0 + 2;
      int c0 = cx0 - bx0 + 2, c1 = cx1 - bx0 + 2;
      v00 = tile[r0 * 22 + c0]; v01 = tile[r0 * 22 + c1];
      v10 = tile[r1 * 22 + c0]; v11 = tile[r1 * 22 + c1];
    } else {
      v00 = xb[cy0 * W + cx0]; v01 = xb[cy0 * W + cx1];
      v10 = xb[cy1 * W + cx0]; v11 = xb[cy1 * W + cx1];
    }
    float val = w00 * v00 + w01 * v01 + w10 * v10 + w11 * v11;
    const float4* wv = (const float4*)&ws1[k * 16];
#pragma unroll
    for (int q = 0; q < 4; ++q) {
      float4 w4 = wv[q];
      acc[4 * q + 0] = fmaf(w4.x, val, acc[4 * q + 0]);
      acc[4 * q + 1] = fmaf(w4.y, val, acc[4 * q + 1]);
      acc[4 * q + 2] = fmaf(w4.z, val, acc[4 * q + 2]);
      acc[4 * q + 3] = fmaf(w4.w, val, acc[4 * q + 3]);
    }
  }

  float4* op = (float4*)(out + (((size_t)b * H + yi) * W + xi) * 16);
#pragma unroll
  for (int q = 0; q < 4; ++q)
    op[q] = make_float4(fmaxf(acc[4 * q + 0], 0.f), fmaxf(acc[4 * q + 1], 0.f),
                        fmaxf(acc[4 * q + 2], 0.f), fmaxf(acc[4 * q + 3], 0.f));
}

// ---- Generic 3x3 conv, NHWC, no activation. Thread per (b,y,x); OC channels.
template <int CIN, int COUT, int NSPLIT>
__global__ __launch_bounds__(256, 4)
void conv3x3_nhwc(const float* __restrict__ in,  // [B,H,W,CIN]
                  const float* __restrict__ w,   // [COUT,CIN,3,3]
                  const float* __restrict__ bias, float* __restrict__ out, // [B,H,W,COUT]
                  int B, int H, int W) {
  constexpr int OC = COUT / NSPLIT;
  __shared__ float ws[9 * CIN * OC];
  int obase = blockIdx.y * OC;
  for (int t = threadIdx.x; t < 9 * CIN * OC; t += 256) {
    int k = t / (CIN * OC); int r = t % (CIN * OC);
    int c = r / OC; int o = r % OC;
    ws[t] = w[((obase + o) * CIN + c) * 9 + k];
  }
  __syncthreads();

  int gid = blockIdx.x * 256 + threadIdx.x;
  if (gid >= B * H * W) return;
  int x = gid % W; int t0 = gid / W; int y = t0 % H; int b = t0 / H;
  const float* inb = in + (size_t)b * H * W * CIN;

  float acc[OC];
#pragma unroll
  for (int o = 0; o < OC; ++o) acc[o] = bias[obase + o];

#pragma unroll
  for (int ky = 0; ky < 3; ++ky) {
    int yy = y + ky - 1;
    if (yy < 0 || yy >= H) continue;
#pragma unroll
    for (int kx = 0; kx < 3; ++kx) {
      int xx = x + kx - 1;
      if (xx < 0 || xx >= W) continue;
      const float4* p4 = (const float4*)(inb + ((size_t)yy * W + xx) * CIN);
      float4 p[CIN / 4];
#pragma unroll
      for (int c4 = 0; c4 < CIN / 4; ++c4) p[c4] = p4[c4];
      int k = ky * 3 + kx;
#pragma unroll
      for (int c4 = 0; c4 < CIN / 4; ++c4) {
        const float* pv = &p[c4].x;
#pragma unroll
        for (int cc = 0; cc < 4; ++cc) {
          const float* wrow = &ws[(k * CIN + 4 * c4 + cc) * OC];
#pragma unroll
          for (int o = 0; o < OC; ++o) acc[o] = fmaf(wrow[o], pv[cc], acc[o]);
        }
      }
    }
  }

  float* op = out + (size_t)gid * COUT + obase;
#pragma unroll
  for (int o = 0; o < OC; ++o) op[o] = acc[o];
}

// ---- Deformable 3x3 conv + ReLU, NHWC. Thread per (b,y,x); OC channels.
template <int CIN, int COUT, int NSPLIT>
__global__ __launch_bounds__(256, 4)
void deform_nhwc(const float* __restrict__ in,     // [B,H,W,CIN]
                 const float* __restrict__ off_in, // [B,H,W,18]
                 const float* __restrict__ w,      // [COUT,CIN,3,3]
                 const float* __restrict__ bias, float* __restrict__ out, // [B,H,W,COUT]
                 int B, int H, int W) {
  constexpr int OC = COUT / NSPLIT;
  __shared__ __align__(16) float ws[9 * CIN * OC];
  int obase = blockIdx.y * OC;
  for (int t = threadIdx.x; t < 9 * CIN * OC; t += 256) {
    int k = t / (CIN * OC); int r = t % (CIN * OC);
    int c = r / OC; int o = r % OC;
    ws[t] = w[((obase + o) * CIN + c) * 9 + k];
  }
  __syncthreads();

  int gid = blockIdx.x * 256 + threadIdx.x;
  if (gid >= B * H * W) return;
  int xi = gid % W; int t0 = gid / W; int yi = t0 % H; int b = t0 / H;
  const float* inb = in + (size_t)b * H * W * CIN;

  float off[18];
  const float2* of2 = (const float2*)(off_in + (size_t)gid * 18);
#pragma unroll
  for (int tt = 0; tt < 9; ++tt) { float2 o2 = of2[tt]; off[2 * tt] = o2.x; off[2 * tt + 1] = o2.y; }

  float acc[OC];
#pragma unroll
  for (int o = 0; o < OC; ++o) acc[o] = bias[obase + o];

#pragma unroll
  for (int k = 0; k < 9; ++k) {
    float py = (float)(yi + k / 3 - 1) + off[2 * k];
    float px = (float)(xi + k % 3 - 1) + off[2 * k + 1];
    float y0f = floorf(py), x0f = floorf(px);
    float fy = py - y0f, fx = px - x0f;
    int y0 = (int)y0f, x0 = (int)x0f, y1 = y0 + 1, x1 = x0 + 1;
    float vy0 = (y0 >= 0 && y0 < H) ? 1.f : 0.f;
    float vy1 = (y1 >= 0 && y1 < H) ? 1.f : 0.f;
    float vx0 = (x0 >= 0 && x0 < W) ? 1.f : 0.f;
    float vx1 = (x1 >= 0 && x1 < W) ? 1.f : 0.f;
    float w00 = (1.f - fy) * (1.f - fx) * vy0 * vx0;
    float w01 = (1.f - fy) * fx * vy0 * vx1;
    float w10 = fy * (1.f - fx) * vy1 * vx0;
    float w11 = fy * fx * vy1 * vx1;
    int cy0 = min(max(y0, 0), H - 1), cy1 = min(max(y1, 0), H - 1);
    int cx0 = min(max(x0, 0), W - 1), cx1 = min(max(x1, 0), W - 1);
    const float4* p00 = (const float4*)(inb + ((size_t)cy0 * W + cx0) * CIN);
    const float4* p01 = (const float4*)(inb + ((size_t)cy0 * W + cx1) * CIN);
    const float4* p10 = (const float4*)(inb + ((size_t)cy1 * W + cx0) * CIN);
    const float4* p11 = (const float4*)(inb + ((size_t)cy1 * W + cx1) * CIN);
#pragma unroll
    for (int c4 = 0; c4 < CIN / 4; ++c4) {
      float4 a = p00[c4], bb = p01[c4], c = p10[c4], d = p11[c4];
      float vals[4];
      vals[0] = w00 * a.x + w01 * bb.x + w10 * c.x + w11 * d.x;
      vals[1] = w00 * a.y + w01 * bb.y + w10 * c.y + w11 * d.y;
      vals[2] = w00 * a.z + w01 * bb.z + w10 * c.z + w11 * d.z;
      vals[3] = w00 * a.w + w01 * bb.w + w10 * c.w + w11 * d.w;
#pragma unroll
      for (int cc = 0; cc < 4; ++cc) {
        const float4* wv = (const float4*)&ws[(k * CIN + 4 * c4 + cc) * OC];
#pragma unroll
        for (int q = 0; q < OC / 4; ++q) {
          float4 w4 = wv[q];
          acc[4 * q + 0] = fmaf(w4.x, vals[cc], acc[4 * q + 0]);
          acc[4 * q + 1] = fmaf(w4.y, vals[cc], acc[4 * q + 1]);
          acc[4 * q + 2] = fmaf(w4.z, vals[cc], acc[4 * q + 2]);
          acc[4 * q + 3] = fmaf(w4.w, vals[cc], acc[4 * q + 3]);
        }
      }
    }
  }

  float* op = out + (size_t)gid * COUT + obase;
#pragma unroll
  for (int q = 0; q < OC / 4; ++q) {
    float4 r = make_float4(fmaxf(acc[4 * q + 0], 0.f), fmaxf(acc[4 * q + 1], 0.f),
                           fmaxf(acc[4 * q + 2], 0.f), fmaxf(acc[4 * q + 3], 0.f));
    *(float4*)(op + 4 * q) = r;
  }
}

// ---- 2x2 stride-2 max pool, NHWC, float4 over channels.
__global__ void maxpool2_nhwc(const float* __restrict__ in, float* __restrict__ out,
                              int B, int C, int H, int W) {
  int Ho = H / 2, Wo = W / 2, C4 = C / 4;
  int gid = blockIdx.x * blockDim.x + threadIdx.x;
  int total = B * Ho * Wo * C4;
  if (gid >= total) return;
  int c4 = gid % C4;
  int t = gid / C4;
  int x = t % Wo; t /= Wo;
  int y = t % Ho;
  int b = t / Ho;
  const float4* p00 = (const float4*)(in + (((size_t)b * H + 2 * y) * W + 2 * x) * C) + c4;
  const float4* p01 = (const float4*)(in + (((size_t)b * H + 2 * y) * W + 2 * x + 1) * C) + c4;
  const float4* p10 = (const float4*)(in + (((size_t)b * H + 2 * y + 1) * W + 2 * x) * C) + c4;
  const float4* p11 = (const float4*)(in + (((size_t)b * H + 2 * y + 1) * W + 2 * x + 1) * C) + c4;
  float4 a = *p00, bb = *p01, c = *p10, d = *p11;
  float4 r;
  r.x = fmaxf(fmaxf(a.x, bb.x), fmaxf(c.x, d.x));
  r.y = fmaxf(fmaxf(a.y, bb.y), fmaxf(c.y, d.y));
  r.z = fmaxf(fmaxf(a.z, bb.z), fmaxf(c.z, d.z));
  r.w = fmaxf(fmaxf(a.w, bb.w), fmaxf(c.w, d.w));
  *((float4*)(out + (((size_t)b * Ho + y) * Wo + x) * C) + c4) = r;
}

// ---- Adaptive avg pool 24->3 (8x8 bins) + fc(576->10), NHWC input.
__global__ void poolfc_nhwc(const float* __restrict__ h,   // [B,24,24,64]
                            const float* __restrict__ wfc, // [10,576]
                            const float* __restrict__ bfc, // [10]
                            float* __restrict__ out) {     // [B,10]
  __shared__ float feat[576];
  int b = blockIdx.x;
  int f = threadIdx.x;        // 576 threads: f = ij*64 + c (coalesced over c)
  int c = f & 63, ij = f >> 6;
  int i = ij / 3, j = ij % 3;
  const float* p = h + (((size_t)b * 24 + i * 8) * 24 + j * 8) * 64 + c;
  float s = 0.f;
#pragma unroll
  for (int r = 0; r < 8; ++r)
#pragma unroll
    for (int q = 0; q < 8; ++q)
      s += p[(r * 24 + q) * 64];
  feat[c * 9 + ij] = s * (1.f / 64.f);
  __syncthreads();
  if (f < 10) {
    float acc = bfc[f];
    const float* wp = wfc + f * 576;
    for (int t = 0; t < 576; ++t) acc = fmaf(wp[t], feat[t], acc);
    out[b * 10 + f] = acc;
  }
}

extern "C" void kernel_launch(void* const* d_in, const int* in_sizes, int n_in,
                              void* d_out, int out_size, void* d_ws, size_t ws_size,
                              hipStream_t stream) {
  const float* x      = (const float*)d_in[0];
  const float* w_off1 = (const float*)d_in[1];
  const float* b_off1 = (const float*)d_in[2];
  const float* w1     = (const float*)d_in[3];
  const float* b1     = (const float*)d_in[4];
  const float* w_off2 = (const float*)d_in[5];
  const float* b_off2 = (const float*)d_in[6];
  const float* w2     = (const float*)d_in[7];
  const float* b2     = (const float*)d_in[8];
  const float* w_off3 = (const float*)d_in[9];
  const float* b_off3 = (const float*)d_in[10];
  const float* w3     = (const float*)d_in[11];
  const float* b3     = (const float*)d_in[12];
  const float* w_fc   = (const float*)d_in[13];
  const float* b_fc   = (const float*)d_in[14];
  float* out = (float*)d_out;

  char* ws = (char*)d_ws;
  float* A  = (float*)(ws);               // NHWC activations (<= 37.75 MB)
  float* Bp = (float*)(ws + 37748736);    // pooled (<= 9.44 MB)
  float* Cp = (float*)(ws + 47185920);    // offsets (<= 10.62 MB)

  const int thr = 256;

  // Layer 1: fused offset+deform+relu -> A [64,96,96,16]
  deform1_fused<<<dim3(36, 64), thr, 0, stream>>>(x, w_off1, b_off1, w1, b1, A);
  // maxpool -> Bp [64,48,48,16]
  {
    int total = 64 * 48 * 48 * (16 / 4);
    maxpool2_nhwc<<<(total + thr - 1) / thr, thr, 0, stream>>>(A, Bp, 64, 16, 96, 96);
  }

  // Layer 2: offset conv -> Cp [64,48,48,18]   (NSPLIT=3, 1728 blocks)
  conv3x3_nhwc<16, 18, 3><<<dim3(576, 3), thr, 0, stream>>>(Bp, w_off2, b_off2, Cp, 64, 48, 48);
  // deform + relu -> A [64,48,48,32]           (NSPLIT=2, 1152 blocks)
  deform_nhwc<16, 32, 2><<<dim3(576, 2), thr, 0, stream>>>(Bp, Cp, w2, b2, A, 64, 48, 48);
  // maxpool -> Bp [64,24,24,32]
  {
    int total = 64 * 24 * 24 * (32 / 4);
    maxpool2_nhwc<<<(total + thr - 1) / thr, thr, 0, stream>>>(A, Bp, 64, 32, 48, 48);
  }

  // Layer 3: offset conv -> Cp [64,24,24,18]   (NSPLIT=6, 864 blocks)
  conv3x3_nhwc<32, 18, 6><<<dim3(144, 6), thr, 0, stream>>>(Bp, w_off3, b_off3, Cp, 64, 24, 24);
  // deform + relu -> A [64,24,24,64]           (NSPLIT=4, 576 blocks)
  deform_nhwc<32, 64, 4><<<dim3(144, 4), thr, 0, stream>>>(Bp, Cp, w3, b3, A, 64, 24, 24);

  // avgpool(3x3) + fc -> out [64,10]
  poolfc_nhwc<<<64, 576, 0, stream>>>(A, w_fc, b_fc, out);
}